// Round 1
// baseline (2427.109 us; speedup 1.0000x reference)
//
#include <hip/hip_runtime.h>
#include <cstddef>

// ---------------------------------------------------------------------------
// SimpleModuleNet: image CNN stem + per-sample expert residual blocks + head.
// B=256, D=64, E=16, H=W=64, PROJ=512, FC=1024, NA=2. All fp32.
//
// Pipeline (fused where a pool follows a conv):
//   p1  = pool(relu(conv3x3(image, stem_w0)+b))          (B,64,32,32)
//   h2  = relu(conv3x3(p1, stem_w[0])+b)                 (B,64,32,32)
//   p2  = pool(relu(conv3x3(h2, stem_w[1])+b))           (B,64,16,16)
//   h   = relu(conv3x3(p2, stem_w[2])+b)                 (B,64,16,16)
//   3x expert rounds (cols 4,5,7):
//     mid = relu(conv3x3(h, w1[idx])+b1[idx])
//     h   = relu(h + conv3x3(mid, w2[idx])+b2[idx])
//   pool3 = pool(relu(conv1x1(h, proj_w)+b))             (B,512,8,8) -> flat k=oc*64+y*8+x
//   fc1o  = relu(pool3 @ fc1_w^T + b)                    (stored transposed [n][m])
//   out   = fc1o @ fc2_w^T + b                           (B,2)
//
// Conv weights are pre-transposed each launch to [ic*9+k][oc] so that
// lane==oc weight loads are coalesced, and LDS input reads are wave-broadcast.
// ---------------------------------------------------------------------------

#define WAVE 64

// ---------------- generic weight transpose  [n][o][i][k] -> [n][(i*K+k)*O+o]
__global__ void transw_k(const float* __restrict__ src, float* __restrict__ dst,
                         int O, int I, int K, int total) {
    int id = blockIdx.x * 256 + threadIdx.x;
    if (id >= total) return;
    int OIK = O * I * K;
    int n = id / OIK, rem = id % OIK;
    int o = rem / (I * K), r2 = rem % (I * K);
    int i = r2 / K, k = r2 % K;
    dst[(size_t)n * OIK + (i * K + k) * O + o] = src[id];
}

// ---------------- conv1: 3->64, 64x64, pad1, +bias, relu, 2x2 maxpool -> 32x32
// block = (b, tile of 16x16 pooled pixels). 256 threads, one pooled pixel each.
__global__ __launch_bounds__(256)
void conv1_k(const float* __restrict__ img, const float* __restrict__ w0t,
             const float* __restrict__ b0, float* __restrict__ out) {
    int b = blockIdx.x, tile = blockIdx.y;
    int typ = (tile >> 1) * 16, txp = (tile & 1) * 16;  // pooled-tile origin in 32x32
    int cy0 = typ * 2, cx0 = txp * 2;                   // conv-region origin (32x32 region)
    __shared__ float lds[3][34][34];
    const float* imb = img + (size_t)b * 3 * 64 * 64;
    for (int i = threadIdx.x; i < 3 * 34 * 34; i += 256) {
        int c = i / 1156, rem = i % 1156, r = rem / 34, cc = rem % 34;
        int gy = cy0 - 1 + r, gx = cx0 - 1 + cc;
        float v = 0.f;
        if (gy >= 0 && gy < 64 && gx >= 0 && gx < 64) v = imb[(c * 64 + gy) * 64 + gx];
        lds[c][r][cc] = v;
    }
    __syncthreads();
    int pyl = threadIdx.x >> 4, pxl = threadIdx.x & 15;
    float win[3][4][4];
#pragma unroll
    for (int c = 0; c < 3; ++c)
#pragma unroll
        for (int wy = 0; wy < 4; ++wy)
#pragma unroll
            for (int wx = 0; wx < 4; ++wx)
                win[c][wy][wx] = lds[c][2 * pyl + wy][2 * pxl + wx];
    int py = typ + pyl, px = txp + pxl;
    for (int oc = 0; oc < 64; ++oc) {
        float a00 = 0, a01 = 0, a10 = 0, a11 = 0;
#pragma unroll
        for (int c = 0; c < 3; ++c)
#pragma unroll
            for (int ky = 0; ky < 3; ++ky)
#pragma unroll
                for (int kx = 0; kx < 3; ++kx) {
                    float w = w0t[(c * 9 + ky * 3 + kx) * 64 + oc];  // wave-uniform -> s_load
                    a00 = fmaf(win[c][0 + ky][0 + kx], w, a00);
                    a01 = fmaf(win[c][0 + ky][1 + kx], w, a01);
                    a10 = fmaf(win[c][1 + ky][0 + kx], w, a10);
                    a11 = fmaf(win[c][1 + ky][1 + kx], w, a11);
                }
        float bv = b0[oc];
        float v = fmaxf(fmaxf(a00 + bv, 0.f), fmaxf(a01 + bv, 0.f));
        v = fmaxf(v, fmaxf(fmaxf(a10 + bv, 0.f), fmaxf(a11 + bv, 0.f)));
        out[(((size_t)b * 64 + oc) * 32 + py) * 32 + px] = v;
    }
}

// ---------------- conv64: 64->64 3x3 pad1 (+bias, optional residual, relu, optional pool)
// block = (b, 8x8 conv tile). 256 threads = 4 waves; lane==oc (all 64 oc per wave),
// each wave owns a 4x4 pixel quadrant -> LDS input reads are 64-lane broadcasts.
// wt layout: [ic*9+k][64 oc] (pre-transposed) -> coalesced lane loads.
template <int S, bool POOL, bool RES>
__global__ __launch_bounds__(256)
void conv64_k(const float* __restrict__ in, float* __restrict__ out,
              const float* __restrict__ wt, const float* __restrict__ bias,
              const float* __restrict__ res,
              const int* __restrict__ question, int qcol) {
    int b = blockIdx.x;
    int tile = blockIdx.y;
    constexpr int NT = S / 8;
    int ty0 = (tile / NT) * 8, tx0 = (tile % NT) * 8;
    __shared__ float lds[64][10][10];
    const float* inb = in + (size_t)b * 64 * S * S;
    for (int i = threadIdx.x; i < 6400; i += 256) {
        int ic = i / 100, rem = i % 100, r = rem / 10, c = rem % 10;
        int gy = ty0 - 1 + r, gx = tx0 - 1 + c;
        float v = 0.f;
        if (gy >= 0 && gy < S && gx >= 0 && gx < S) v = inb[(ic * S + gy) * S + gx];
        lds[ic][r][c] = v;
    }
    __syncthreads();
    int lane = threadIdx.x & 63;
    int wv = threadIdx.x >> 6;
    int qy = (wv >> 1) * 4, qx = (wv & 1) * 4;
    const float* wtb = wt;
    const float* bb = bias;
    if (question) {
        int idx = question[b * 8 + qcol];
        wtb += (size_t)idx * 576 * 64;
        bb += idx * 64;
    }
    float bval = bb[lane];
    float acc[4][4] = {};
    for (int ic = 0; ic < 64; ++ic) {
        float win[6][6];
#pragma unroll
        for (int r = 0; r < 6; ++r)
#pragma unroll
            for (int c = 0; c < 6; ++c)
                win[r][c] = lds[ic][qy + r][qx + c];   // broadcast (same addr all lanes)
        float w9[9];
#pragma unroll
        for (int k = 0; k < 9; ++k) w9[k] = wtb[(ic * 9 + k) * 64 + lane];  // coalesced
#pragma unroll
        for (int ky = 0; ky < 3; ++ky)
#pragma unroll
            for (int kx = 0; kx < 3; ++kx) {
                float wvv = w9[ky * 3 + kx];
#pragma unroll
                for (int py = 0; py < 4; ++py)
#pragma unroll
                    for (int px = 0; px < 4; ++px)
                        acc[py][px] = fmaf(win[py + ky][px + kx], wvv, acc[py][px]);
            }
    }
    size_t ocbase = (size_t)b * 64 + lane;
    if (!POOL) {
#pragma unroll
        for (int py = 0; py < 4; ++py)
#pragma unroll
            for (int px = 0; px < 4; ++px) {
                float v = acc[py][px] + bval;
                if (RES) v += res[(ocbase * S + (ty0 + qy + py)) * S + (tx0 + qx + px)];
                out[(ocbase * S + (ty0 + qy + py)) * S + (tx0 + qx + px)] = fmaxf(v, 0.f);
            }
    } else {
        constexpr int SP = S / 2;
#pragma unroll
        for (int ppy = 0; ppy < 2; ++ppy)
#pragma unroll
            for (int ppx = 0; ppx < 2; ++ppx) {
                float m0 = fmaxf(fmaxf(acc[2 * ppy][2 * ppx] + bval, 0.f),
                                 fmaxf(acc[2 * ppy][2 * ppx + 1] + bval, 0.f));
                float m1 = fmaxf(fmaxf(acc[2 * ppy + 1][2 * ppx] + bval, 0.f),
                                 fmaxf(acc[2 * ppy + 1][2 * ppx + 1] + bval, 0.f));
                out[(ocbase * SP + ((ty0 + qy) / 2 + ppy)) * SP + ((tx0 + qx) / 2 + ppx)] =
                    fmaxf(m0, m1);
            }
    }
}

// ---------------- proj: 1x1 conv 64->512 + bias + relu + 2x2 pool -> (B,512,8,8)
// block = (b, oc-half). Whole input sample staged in LDS (64 KiB).
__global__ __launch_bounds__(256)
void proj_k(const float* __restrict__ in, const float* __restrict__ wt /*[64][512]*/,
            const float* __restrict__ bias, float* __restrict__ out) {
    int b = blockIdx.x;
    __shared__ float lds[64 * 256];
    const float* inb = in + (size_t)b * 16384;
    for (int i = threadIdx.x; i < 16384; i += 256) lds[i] = inb[i];
    __syncthreads();
    int p = threadIdx.x & 63, py = p >> 3, px = p & 7;
    int g = __builtin_amdgcn_readfirstlane(threadIdx.x >> 6);  // wave id -> SGPR
    int ocb = blockIdx.y * 256 + g * 64;
    for (int cc = 0; cc < 8; ++cc) {  // 8 oc per chunk
        float acc[8][4] = {};
        for (int icc = 0; icc < 8; ++icc) {  // 8 ic per subchunk
            float v[8][4];
#pragma unroll
            for (int i = 0; i < 8; ++i) {
                int ic = icc * 8 + i;
#pragma unroll
                for (int d = 0; d < 4; ++d) {
                    int cy = 2 * py + (d >> 1), cx = 2 * px + (d & 1);
                    v[i][d] = lds[ic * 256 + cy * 16 + cx];
                }
            }
#pragma unroll
            for (int i = 0; i < 8; ++i)
#pragma unroll
                for (int o = 0; o < 8; ++o) {
                    float w = wt[(icc * 8 + i) * 512 + ocb + cc * 8 + o];  // uniform
#pragma unroll
                    for (int d = 0; d < 4; ++d) acc[o][d] = fmaf(v[i][d], w, acc[o][d]);
                }
        }
#pragma unroll
        for (int o = 0; o < 8; ++o) {
            int oc = ocb + cc * 8 + o;
            float bv = bias[oc];
            float m = fmaxf(fmaxf(acc[o][0] + bv, 0.f), fmaxf(acc[o][1] + bv, 0.f));
            m = fmaxf(m, fmaxf(fmaxf(acc[o][2] + bv, 0.f), fmaxf(acc[o][3] + bv, 0.f)));
            out[(size_t)b * 32768 + (size_t)oc * 64 + p] = m;  // flatten k = oc*64+y*8+x
        }
    }
}

// ---------------- fc1: [256][32768] @ [1024][32768]^T, split-K=16, partials out.
// block = (n-group of 32, k-chunk of 2048). Activations LDS-transposed so
// compute reads are conflict-free with lane==m; W reads are wave-uniform (s_load).
__global__ __launch_bounds__(256)
void fc1_k(const float* __restrict__ act, const float* __restrict__ W,
           float* __restrict__ partial /* [n][16][256] */) {
    int n0 = blockIdx.x * 32;
    int ks = blockIdx.y;
    int m = threadIdx.x;
    __shared__ float lds_a[32][257];
    float acc[32] = {};
    for (int kt = 0; kt < 64; ++kt) {
        int k0 = ks * 2048 + kt * 32;
        __syncthreads();
        for (int i = threadIdx.x; i < 256 * 32; i += 256) {
            int mm = i >> 5, kk = i & 31;
            lds_a[kk][mm] = act[(size_t)mm * 32768 + k0 + kk];
        }
        __syncthreads();
#pragma unroll 4
        for (int kk = 0; kk < 32; ++kk) {
            float a = lds_a[kk][m];
            const float* wr = W + (size_t)n0 * 32768 + k0 + kk;
#pragma unroll
            for (int j = 0; j < 32; ++j)
                acc[j] = fmaf(a, wr[(size_t)j * 32768], acc[j]);
        }
    }
    for (int j = 0; j < 32; ++j)
        partial[((size_t)(n0 + j) * 16 + ks) * 256 + m] = acc[j];
}

__global__ __launch_bounds__(256)
void fc1red_k(const float* __restrict__ partial, const float* __restrict__ b1,
              float* __restrict__ fc1o_t /* [n][m] */) {
    int n = blockIdx.x;
    int m = threadIdx.x;
    float s = b1[n];
#pragma unroll
    for (int ks = 0; ks < 16; ++ks) s += partial[((size_t)n * 16 + ks) * 256 + m];
    fc1o_t[(size_t)n * 256 + m] = fmaxf(s, 0.f);
}

// ---------------- fc2: [256][1024] @ [2][1024]^T + b  (reads transposed fc1o)
__global__ __launch_bounds__(256)
void fc2a_k(const float* __restrict__ a_t /*[1024][256]*/, const float* __restrict__ W2,
            float* __restrict__ p2) {
    int n2 = blockIdx.x, ks = blockIdx.y;  // grid (2,4)
    int m = threadIdx.x;
    float acc = 0.f;
    for (int k = ks * 256; k < ks * 256 + 256; ++k)
        acc = fmaf(a_t[(size_t)k * 256 + m], W2[n2 * 1024 + k], acc);
    p2[((size_t)n2 * 4 + ks) * 256 + m] = acc;
}

__global__ __launch_bounds__(512)
void fc2b_k(const float* __restrict__ p2, const float* __restrict__ b2,
            float* __restrict__ out) {
    int i = threadIdx.x;  // 512
    int m = i >> 1, n2 = i & 1;
    float s = b2[n2];
#pragma unroll
    for (int ks = 0; ks < 4; ++ks) s += p2[((size_t)n2 * 4 + ks) * 256 + m];
    out[m * 2 + n2] = s;
}

// ---------------------------------------------------------------------------
extern "C" void kernel_launch(void* const* d_in, const int* in_sizes, int n_in,
                              void* d_out, int out_size, void* d_ws, size_t ws_size,
                              hipStream_t stream) {
    const float* image   = (const float*)d_in[0];
    const int*   question= (const int*)d_in[1];
    const float* stem_w0 = (const float*)d_in[2];
    const float* stem_b0 = (const float*)d_in[3];
    const float* stem_w  = (const float*)d_in[4];
    const float* stem_b  = (const float*)d_in[5];
    const float* exp_w1  = (const float*)d_in[6];
    const float* exp_b1  = (const float*)d_in[7];
    const float* exp_w2  = (const float*)d_in[8];
    const float* exp_b2  = (const float*)d_in[9];
    const float* proj_w  = (const float*)d_in[10];
    const float* proj_b  = (const float*)d_in[11];
    const float* fc1_w   = (const float*)d_in[12];
    const float* fc1_b   = (const float*)d_in[13];
    const float* fc2_w   = (const float*)d_in[14];
    const float* fc2_b   = (const float*)d_in[15];
    (void)in_sizes; (void)n_in; (void)out_size; (void)ws_size;

    float* ws = (float*)d_ws;
    // Workspace plan (floats). Peak usage ~149 MB.
    //   [0 , A)        p1 (B,64,32,32); later: hA/hB/hC rotation (3*P2N), then fc1 partials
    //   [A , 2A)       h2 (B,64,32,32); later: pool3 (8.39M) + fc1o_t (0.26M)
    //   [2A, 2A+P2N)   p2 (B,64,16,16)
    //   [2A+P2N, ...)  transposed weights + fc2 partials
    const size_t A = 16777216, P2N = 4194304;
    float* p1    = ws;
    float* h2    = ws + A;
    float* p2    = ws + 2 * A;
    float* wtr   = ws + 2 * A + P2N;
    float* w0t   = wtr;                    // 1728
    float* stemt = wtr + 1728;             // 3*36864 = 110592
    float* e1t   = stemt + 110592;         // 589824
    float* e2t   = e1t + 589824;           // 589824
    float* projt = e2t + 589824;           // 32768
    float* pfc2  = projt + 32768;          // 2048
    float* hA    = ws;                     // aliases p1 (dead by then)
    float* hB    = ws + P2N;
    float* hC    = ws + 2 * P2N;
    float* pool3 = h2;                     // aliases h2 (dead by then)
    float* fc1o  = h2 + 8388608;           // 262144 floats
    float* fc1p  = ws;                     // fc1 partials [1024][16][256], aliases hA (dead)

    // --- one-time (per launch) weight transposes to [ic*9+k][oc] ---
    transw_k<<<(1728 + 255) / 256, 256, 0, stream>>>(stem_w0, w0t, 64, 3, 9, 1728);
    transw_k<<<(110592 + 255) / 256, 256, 0, stream>>>(stem_w, stemt, 64, 64, 9, 110592);
    transw_k<<<(589824 + 255) / 256, 256, 0, stream>>>(exp_w1, e1t, 64, 64, 9, 589824);
    transw_k<<<(589824 + 255) / 256, 256, 0, stream>>>(exp_w2, e2t, 64, 64, 9, 589824);
    transw_k<<<(32768 + 255) / 256, 256, 0, stream>>>(proj_w, projt, 512, 64, 1, 32768);

    // --- stem ---
    conv1_k<<<dim3(256, 4), 256, 0, stream>>>(image, w0t, stem_b0, p1);
    conv64_k<32, false, false><<<dim3(256, 16), 256, 0, stream>>>(
        p1, h2, stemt, stem_b, nullptr, nullptr, 0);
    conv64_k<32, true, false><<<dim3(256, 16), 256, 0, stream>>>(
        h2, p2, stemt + 36864, stem_b + 64, nullptr, nullptr, 0);
    conv64_k<16, false, false><<<dim3(256, 4), 256, 0, stream>>>(
        p2, hA, stemt + 2 * 36864, stem_b + 128, nullptr, nullptr, 0);

    // --- expert residual rounds (question cols 4,5,7) ---
    const int cols[3] = {4, 5, 7};
    float* hin = hA;
    float* hmid = hB;
    float* hout = hC;
    for (int r = 0; r < 3; ++r) {
        conv64_k<16, false, false><<<dim3(256, 4), 256, 0, stream>>>(
            hin, hmid, e1t, exp_b1, nullptr, question, cols[r]);
        conv64_k<16, false, true><<<dim3(256, 4), 256, 0, stream>>>(
            hmid, hout, e2t, exp_b2, hin, question, cols[r]);
        float* t = hin; hin = hout; hout = hmid; hmid = t;
    }
    // hin == final h (at ws+0)

    // --- head ---
    proj_k<<<dim3(256, 2), 256, 0, stream>>>(hin, projt, proj_b, pool3);
    fc1_k<<<dim3(32, 16), 256, 0, stream>>>(pool3, fc1_w, fc1p);
    fc1red_k<<<1024, 256, 0, stream>>>(fc1p, fc1_b, fc1o);
    fc2a_k<<<dim3(2, 4), 256, 0, stream>>>(fc1o, fc2_w, pfc2);
    fc2b_k<<<1, 512, 0, stream>>>(pfc2, fc2_b, (float*)d_out);
}

// Round 2
// 1416.686 us; speedup vs baseline: 1.7132x; 1.7132x over previous
//
#include <hip/hip_runtime.h>
#include <cstddef>

// ---------------------------------------------------------------------------
// SimpleModuleNet: image CNN stem + per-sample expert residual blocks + head.
// B=256, D=64, E=16, H=W=64, PROJ=512, FC=1024, NA=2. All fp32.
//
//   p1  = pool(relu(conv3x3(image, stem_w0)+b))          (B,64,32,32)
//   h2  = relu(conv3x3(p1, stem_w[0])+b)                 (B,64,32,32)
//   p2  = pool(relu(conv3x3(h2, stem_w[1])+b))           (B,64,16,16)
//   h   = relu(conv3x3(p2, stem_w[2])+b)                 (B,64,16,16)
//   3x expert rounds (cols 4,5,7):
//     mid = relu(conv3x3(h, w1[idx])+b1[idx])
//     h   = relu(h + conv3x3(mid, w2[idx])+b2[idx])
//   pool3 = pool(relu(conv1x1(h, proj_w)+b))             (B,512,8,8) -> flat k=oc*64+y*8+x
//   fc1o  = relu(pool3 @ fc1_w^T + b)                    (stored transposed [n][m])
//   out   = fc1o @ fc2_w^T + b                           (B,2)
//
// R1 change: fc1 rewritten as register-blocked split-K GEMM (was latency-bound
// scalar-load loop at 21% VALUBusy, 1250us; compute floor is ~110us).
// ---------------------------------------------------------------------------

// ---------------- generic weight transpose  [n][o][i][k] -> [n][(i*K+k)*O+o]
__global__ void transw_k(const float* __restrict__ src, float* __restrict__ dst,
                         int O, int I, int K, int total) {
    int id = blockIdx.x * 256 + threadIdx.x;
    if (id >= total) return;
    int OIK = O * I * K;
    int n = id / OIK, rem = id % OIK;
    int o = rem / (I * K), r2 = rem % (I * K);
    int i = r2 / K, k = r2 % K;
    dst[(size_t)n * OIK + (i * K + k) * O + o] = src[id];
}

// ---------------- conv1: 3->64, 64x64, pad1, +bias, relu, 2x2 maxpool -> 32x32
__global__ __launch_bounds__(256)
void conv1_k(const float* __restrict__ img, const float* __restrict__ w0t,
             const float* __restrict__ b0, float* __restrict__ out) {
    int b = blockIdx.x, tile = blockIdx.y;
    int typ = (tile >> 1) * 16, txp = (tile & 1) * 16;
    int cy0 = typ * 2, cx0 = txp * 2;
    __shared__ float lds[3][34][34];
    const float* imb = img + (size_t)b * 3 * 64 * 64;
    for (int i = threadIdx.x; i < 3 * 34 * 34; i += 256) {
        int c = i / 1156, rem = i % 1156, r = rem / 34, cc = rem % 34;
        int gy = cy0 - 1 + r, gx = cx0 - 1 + cc;
        float v = 0.f;
        if (gy >= 0 && gy < 64 && gx >= 0 && gx < 64) v = imb[(c * 64 + gy) * 64 + gx];
        lds[c][r][cc] = v;
    }
    __syncthreads();
    int pyl = threadIdx.x >> 4, pxl = threadIdx.x & 15;
    float win[3][4][4];
#pragma unroll
    for (int c = 0; c < 3; ++c)
#pragma unroll
        for (int wy = 0; wy < 4; ++wy)
#pragma unroll
            for (int wx = 0; wx < 4; ++wx)
                win[c][wy][wx] = lds[c][2 * pyl + wy][2 * pxl + wx];
    int py = typ + pyl, px = txp + pxl;
    for (int oc = 0; oc < 64; ++oc) {
        float a00 = 0, a01 = 0, a10 = 0, a11 = 0;
#pragma unroll
        for (int c = 0; c < 3; ++c)
#pragma unroll
            for (int ky = 0; ky < 3; ++ky)
#pragma unroll
                for (int kx = 0; kx < 3; ++kx) {
                    float w = w0t[(c * 9 + ky * 3 + kx) * 64 + oc];
                    a00 = fmaf(win[c][0 + ky][0 + kx], w, a00);
                    a01 = fmaf(win[c][0 + ky][1 + kx], w, a01);
                    a10 = fmaf(win[c][1 + ky][0 + kx], w, a10);
                    a11 = fmaf(win[c][1 + ky][1 + kx], w, a11);
                }
        float bv = b0[oc];
        float v = fmaxf(fmaxf(a00 + bv, 0.f), fmaxf(a01 + bv, 0.f));
        v = fmaxf(v, fmaxf(fmaxf(a10 + bv, 0.f), fmaxf(a11 + bv, 0.f)));
        out[(((size_t)b * 64 + oc) * 32 + py) * 32 + px] = v;
    }
}

// ---------------- conv64: 64->64 3x3 pad1 (+bias, optional residual, relu, optional pool)
template <int S, bool POOL, bool RES>
__global__ __launch_bounds__(256)
void conv64_k(const float* __restrict__ in, float* __restrict__ out,
              const float* __restrict__ wt, const float* __restrict__ bias,
              const float* __restrict__ res,
              const int* __restrict__ question, int qcol) {
    int b = blockIdx.x;
    int tile = blockIdx.y;
    constexpr int NT = S / 8;
    int ty0 = (tile / NT) * 8, tx0 = (tile % NT) * 8;
    __shared__ float lds[64][10][10];
    const float* inb = in + (size_t)b * 64 * S * S;
    for (int i = threadIdx.x; i < 6400; i += 256) {
        int ic = i / 100, rem = i % 100, r = rem / 10, c = rem % 10;
        int gy = ty0 - 1 + r, gx = tx0 - 1 + c;
        float v = 0.f;
        if (gy >= 0 && gy < S && gx >= 0 && gx < S) v = inb[(ic * S + gy) * S + gx];
        lds[ic][r][c] = v;
    }
    __syncthreads();
    int lane = threadIdx.x & 63;
    int wv = threadIdx.x >> 6;
    int qy = (wv >> 1) * 4, qx = (wv & 1) * 4;
    const float* wtb = wt;
    const float* bb = bias;
    if (question) {
        int idx = question[b * 8 + qcol];
        wtb += (size_t)idx * 576 * 64;
        bb += idx * 64;
    }
    float bval = bb[lane];
    float acc[4][4] = {};
    for (int ic = 0; ic < 64; ++ic) {
        float win[6][6];
#pragma unroll
        for (int r = 0; r < 6; ++r)
#pragma unroll
            for (int c = 0; c < 6; ++c)
                win[r][c] = lds[ic][qy + r][qx + c];
        float w9[9];
#pragma unroll
        for (int k = 0; k < 9; ++k) w9[k] = wtb[(ic * 9 + k) * 64 + lane];
#pragma unroll
        for (int ky = 0; ky < 3; ++ky)
#pragma unroll
            for (int kx = 0; kx < 3; ++kx) {
                float wvv = w9[ky * 3 + kx];
#pragma unroll
                for (int py = 0; py < 4; ++py)
#pragma unroll
                    for (int px = 0; px < 4; ++px)
                        acc[py][px] = fmaf(win[py + ky][px + kx], wvv, acc[py][px]);
            }
    }
    size_t ocbase = (size_t)b * 64 + lane;
    if (!POOL) {
#pragma unroll
        for (int py = 0; py < 4; ++py)
#pragma unroll
            for (int px = 0; px < 4; ++px) {
                float v = acc[py][px] + bval;
                if (RES) v += res[(ocbase * S + (ty0 + qy + py)) * S + (tx0 + qx + px)];
                out[(ocbase * S + (ty0 + qy + py)) * S + (tx0 + qx + px)] = fmaxf(v, 0.f);
            }
    } else {
        constexpr int SP = S / 2;
#pragma unroll
        for (int ppy = 0; ppy < 2; ++ppy)
#pragma unroll
            for (int ppx = 0; ppx < 2; ++ppx) {
                float m0 = fmaxf(fmaxf(acc[2 * ppy][2 * ppx] + bval, 0.f),
                                 fmaxf(acc[2 * ppy][2 * ppx + 1] + bval, 0.f));
                float m1 = fmaxf(fmaxf(acc[2 * ppy + 1][2 * ppx] + bval, 0.f),
                                 fmaxf(acc[2 * ppy + 1][2 * ppx + 1] + bval, 0.f));
                out[(ocbase * SP + ((ty0 + qy) / 2 + ppy)) * SP + ((tx0 + qx) / 2 + ppx)] =
                    fmaxf(m0, m1);
            }
    }
}

// ---------------- proj: 1x1 conv 64->512 + bias + relu + 2x2 pool -> (B,512,8,8)
__global__ __launch_bounds__(256)
void proj_k(const float* __restrict__ in, const float* __restrict__ wt /*[64][512]*/,
            const float* __restrict__ bias, float* __restrict__ out) {
    int b = blockIdx.x;
    __shared__ float lds[64 * 256];
    const float* inb = in + (size_t)b * 16384;
    for (int i = threadIdx.x; i < 16384; i += 256) lds[i] = inb[i];
    __syncthreads();
    int p = threadIdx.x & 63, py = p >> 3, px = p & 7;
    int g = __builtin_amdgcn_readfirstlane(threadIdx.x >> 6);
    int ocb = blockIdx.y * 256 + g * 64;
    for (int cc = 0; cc < 8; ++cc) {
        float acc[8][4] = {};
        for (int icc = 0; icc < 8; ++icc) {
            float v[8][4];
#pragma unroll
            for (int i = 0; i < 8; ++i) {
                int ic = icc * 8 + i;
#pragma unroll
                for (int d = 0; d < 4; ++d) {
                    int cy = 2 * py + (d >> 1), cx = 2 * px + (d & 1);
                    v[i][d] = lds[ic * 256 + cy * 16 + cx];
                }
            }
#pragma unroll
            for (int i = 0; i < 8; ++i)
#pragma unroll
                for (int o = 0; o < 8; ++o) {
                    float w = wt[(icc * 8 + i) * 512 + ocb + cc * 8 + o];
#pragma unroll
                    for (int d = 0; d < 4; ++d) acc[o][d] = fmaf(v[i][d], w, acc[o][d]);
                }
        }
#pragma unroll
        for (int o = 0; o < 8; ++o) {
            int oc = ocb + cc * 8 + o;
            float bv = bias[oc];
            float m = fmaxf(fmaxf(acc[o][0] + bv, 0.f), fmaxf(acc[o][1] + bv, 0.f));
            m = fmaxf(m, fmaxf(fmaxf(acc[o][2] + bv, 0.f), fmaxf(acc[o][3] + bv, 0.f)));
            out[(size_t)b * 32768 + (size_t)oc * 64 + p] = m;
        }
    }
}

// ---------------- fc1 GEMM: C[256][1024] = A[256][32768] @ W[1024][32768]^T
// Register-blocked split-K: block tile 128m x 128n, K-split 64 chunks of 512.
// Grid 1024 blocks (ordered ks-major for L2 tile sharing), 256 threads,
// 8x8 micro-tile (split as {tx*4..+3, 64+tx*4..+3} -> 2-way LDS aliasing only).
__global__ __launch_bounds__(256, 4)
void fc1gemm_k(const float* __restrict__ A, const float* __restrict__ W,
               float* __restrict__ partial /* [64][256][1024] */) {
    int bid = blockIdx.x;
    int mt = bid & 1;
    int nt = (bid >> 1) & 7;
    int ks = bid >> 4;
    int m0 = mt * 128, n0 = nt * 128, k0 = ks * 512;
    __shared__ float sa[32][128];  // [k][m]
    __shared__ float sb[32][128];  // [k][n]
    int tx = threadIdx.x & 15, ty = threadIdx.x >> 4;
    float acc[8][8] = {};
    for (int kt = 0; kt < 16; ++kt) {
        int kk0 = k0 + kt * 32;
        __syncthreads();
#pragma unroll
        for (int pass = 0; pass < 4; ++pass) {
            int idx = pass * 256 + threadIdx.x;
            int row = idx >> 3, c4 = (idx & 7) << 2;
            float4 av = *(const float4*)&A[(size_t)(m0 + row) * 32768 + kk0 + c4];
            sa[c4 + 0][row] = av.x; sa[c4 + 1][row] = av.y;
            sa[c4 + 2][row] = av.z; sa[c4 + 3][row] = av.w;
            float4 wv = *(const float4*)&W[(size_t)(n0 + row) * 32768 + kk0 + c4];
            sb[c4 + 0][row] = wv.x; sb[c4 + 1][row] = wv.y;
            sb[c4 + 2][row] = wv.z; sb[c4 + 3][row] = wv.w;
        }
        __syncthreads();
#pragma unroll 8
        for (int kk = 0; kk < 32; ++kk) {
            float a[8], b[8];
            *(float4*)&a[0] = *(const float4*)&sa[kk][ty * 4];
            *(float4*)&a[4] = *(const float4*)&sa[kk][64 + ty * 4];
            *(float4*)&b[0] = *(const float4*)&sb[kk][tx * 4];
            *(float4*)&b[4] = *(const float4*)&sb[kk][64 + tx * 4];
#pragma unroll
            for (int i = 0; i < 8; ++i)
#pragma unroll
                for (int j = 0; j < 8; ++j)
                    acc[i][j] = fmaf(a[i], b[j], acc[i][j]);
        }
    }
#pragma unroll
    for (int i = 0; i < 8; ++i) {
        int m = m0 + ((i < 4) ? ty * 4 + i : 64 + ty * 4 + (i - 4));
#pragma unroll
        for (int jh = 0; jh < 2; ++jh) {
            int n = n0 + jh * 64 + tx * 4;
            float4 v = {acc[i][jh * 4 + 0], acc[i][jh * 4 + 1],
                        acc[i][jh * 4 + 2], acc[i][jh * 4 + 3]};
            *(float4*)&partial[((size_t)ks * 256 + m) * 1024 + n] = v;
        }
    }
}

// reduce 64 partials + bias + relu, store transposed [n][m] for fc2.
__global__ __launch_bounds__(256)
void fc1red_k(const float* __restrict__ partial, const float* __restrict__ b1,
              float* __restrict__ fc1o_t /* [n][m] */) {
    int m = blockIdx.x;       // 256
    int n0 = threadIdx.x * 4; // 256 threads x 4 n
    float4 s = {0.f, 0.f, 0.f, 0.f};
    for (int ks = 0; ks < 64; ++ks) {
        float4 v = *(const float4*)&partial[((size_t)ks * 256 + m) * 1024 + n0];
        s.x += v.x; s.y += v.y; s.z += v.z; s.w += v.w;
    }
    fc1o_t[(size_t)(n0 + 0) * 256 + m] = fmaxf(s.x + b1[n0 + 0], 0.f);
    fc1o_t[(size_t)(n0 + 1) * 256 + m] = fmaxf(s.y + b1[n0 + 1], 0.f);
    fc1o_t[(size_t)(n0 + 2) * 256 + m] = fmaxf(s.z + b1[n0 + 2], 0.f);
    fc1o_t[(size_t)(n0 + 3) * 256 + m] = fmaxf(s.w + b1[n0 + 3], 0.f);
}

// ---------------- fc2: [256][1024] @ [2][1024]^T + b  (reads transposed fc1o)
__global__ __launch_bounds__(256)
void fc2a_k(const float* __restrict__ a_t /*[1024][256]*/, const float* __restrict__ W2,
            float* __restrict__ p2) {
    int n2 = blockIdx.x, ks = blockIdx.y;  // grid (2,4)
    int m = threadIdx.x;
    float acc = 0.f;
    for (int k = ks * 256; k < ks * 256 + 256; ++k)
        acc = fmaf(a_t[(size_t)k * 256 + m], W2[n2 * 1024 + k], acc);
    p2[((size_t)n2 * 4 + ks) * 256 + m] = acc;
}

__global__ __launch_bounds__(512)
void fc2b_k(const float* __restrict__ p2, const float* __restrict__ b2,
            float* __restrict__ out) {
    int i = threadIdx.x;  // 512
    int m = i >> 1, n2 = i & 1;
    float s = b2[n2];
#pragma unroll
    for (int ks = 0; ks < 4; ++ks) s += p2[((size_t)n2 * 4 + ks) * 256 + m];
    out[m * 2 + n2] = s;
}

// ---------------------------------------------------------------------------
extern "C" void kernel_launch(void* const* d_in, const int* in_sizes, int n_in,
                              void* d_out, int out_size, void* d_ws, size_t ws_size,
                              hipStream_t stream) {
    const float* image   = (const float*)d_in[0];
    const int*   question= (const int*)d_in[1];
    const float* stem_w0 = (const float*)d_in[2];
    const float* stem_b0 = (const float*)d_in[3];
    const float* stem_w  = (const float*)d_in[4];
    const float* stem_b  = (const float*)d_in[5];
    const float* exp_w1  = (const float*)d_in[6];
    const float* exp_b1  = (const float*)d_in[7];
    const float* exp_w2  = (const float*)d_in[8];
    const float* exp_b2  = (const float*)d_in[9];
    const float* proj_w  = (const float*)d_in[10];
    const float* proj_b  = (const float*)d_in[11];
    const float* fc1_w   = (const float*)d_in[12];
    const float* fc1_b   = (const float*)d_in[13];
    const float* fc2_w   = (const float*)d_in[14];
    const float* fc2_b   = (const float*)d_in[15];
    (void)in_sizes; (void)n_in; (void)out_size; (void)ws_size;

    float* ws = (float*)d_ws;
    // Workspace plan (floats). Peak ~150 MB.
    //   [0 , A)        p1 (64MiB); later hA/hB/hC rotation (3*P2N=48MiB);
    //                  after proj: fc1 partials [64][256][1024] (exactly A floats)
    //   [A , 2A)       h2 (64MiB); later pool3 (32MiB) + fc1o_t (1MiB)
    //   [2A, 2A+P2N)   p2 (16MiB)
    //   [2A+P2N, ...)  transposed weights + fc2 partials
    const size_t A = 16777216, P2N = 4194304;
    float* p1    = ws;
    float* h2    = ws + A;
    float* p2    = ws + 2 * A;
    float* wtr   = ws + 2 * A + P2N;
    float* w0t   = wtr;                    // 1728
    float* stemt = wtr + 1728;             // 110592
    float* e1t   = stemt + 110592;         // 589824
    float* e2t   = e1t + 589824;           // 589824
    float* projt = e2t + 589824;           // 32768
    float* pfc2  = projt + 32768;          // 2048
    float* hA    = ws;                     // aliases p1 (dead)
    float* hB    = ws + P2N;
    float* hC    = ws + 2 * P2N;
    float* pool3 = h2;                     // aliases h2 (dead)
    float* fc1o  = h2 + 8388608;           // 262144 floats
    float* fc1p  = ws;                     // fc1 partials, aliases hA (dead after proj)

    transw_k<<<(1728 + 255) / 256, 256, 0, stream>>>(stem_w0, w0t, 64, 3, 9, 1728);
    transw_k<<<(110592 + 255) / 256, 256, 0, stream>>>(stem_w, stemt, 64, 64, 9, 110592);
    transw_k<<<(589824 + 255) / 256, 256, 0, stream>>>(exp_w1, e1t, 64, 64, 9, 589824);
    transw_k<<<(589824 + 255) / 256, 256, 0, stream>>>(exp_w2, e2t, 64, 64, 9, 589824);
    transw_k<<<(32768 + 255) / 256, 256, 0, stream>>>(proj_w, projt, 512, 64, 1, 32768);

    conv1_k<<<dim3(256, 4), 256, 0, stream>>>(image, w0t, stem_b0, p1);
    conv64_k<32, false, false><<<dim3(256, 16), 256, 0, stream>>>(
        p1, h2, stemt, stem_b, nullptr, nullptr, 0);
    conv64_k<32, true, false><<<dim3(256, 16), 256, 0, stream>>>(
        h2, p2, stemt + 36864, stem_b + 64, nullptr, nullptr, 0);
    conv64_k<16, false, false><<<dim3(256, 4), 256, 0, stream>>>(
        p2, hA, stemt + 2 * 36864, stem_b + 128, nullptr, nullptr, 0);

    const int cols[3] = {4, 5, 7};
    float* hin = hA;
    float* hmid = hB;
    float* hout = hC;
    for (int r = 0; r < 3; ++r) {
        conv64_k<16, false, false><<<dim3(256, 4), 256, 0, stream>>>(
            hin, hmid, e1t, exp_b1, nullptr, question, cols[r]);
        conv64_k<16, false, true><<<dim3(256, 4), 256, 0, stream>>>(
            hmid, hout, e2t, exp_b2, hin, question, cols[r]);
        float* t = hin; hin = hout; hout = hmid; hmid = t;
    }
    // hin == final h (at ws+0)

    proj_k<<<dim3(256, 2), 256, 0, stream>>>(hin, projt, proj_b, pool3);
    fc1gemm_k<<<1024, 256, 0, stream>>>(pool3, fc1_w, fc1p);
    fc1red_k<<<256, 256, 0, stream>>>(fc1p, fc1_b, fc1o);
    fc2a_k<<<dim3(2, 4), 256, 0, stream>>>(fc1o, fc2_w, pfc2);
    fc2b_k<<<1, 512, 0, stream>>>(pfc2, fc2_b, (float*)d_out);
}

// Round 3
// 668.198 us; speedup vs baseline: 3.6323x; 2.1202x over previous
//
#include <hip/hip_runtime.h>
#include <cstddef>

// ---------------------------------------------------------------------------
// SimpleModuleNet. B=256, D=64, E=16, H=W=64, PROJ=512, FC=1024, NA=2.
//
// R2 change: all 64->64 3x3 convs run on the matrix pipe via
// mfma_f32_16x16x32_f16 with an f16 hi/lo split (3 MFMAs / logical MAC,
// lo plane pre-scaled by 2048 -> error ~2^-22, near-fp32).
// Activations are NHWC fp32; weights pre-transformed to B-fragment order.
// Conv epilogues fuse bias/relu/residual/2x2-maxpool.
// ---------------------------------------------------------------------------

typedef _Float16 half8 __attribute__((ext_vector_type(8)));
typedef _Float16 half4_t __attribute__((ext_vector_type(4)));
typedef float f32x4 __attribute__((ext_vector_type(4)));

#define LO_SCALE 2048.0f
#define LO_INV (1.0f / 2048.0f)

// ---------------- generic weight transpose  [o][i](1x1) -> [i][o]  (proj)
__global__ void transw_k(const float* __restrict__ src, float* __restrict__ dst,
                         int O, int I, int K, int total) {
    int id = blockIdx.x * 256 + threadIdx.x;
    if (id >= total) return;
    int OIK = O * I * K;
    int n = id / OIK, rem = id % OIK;
    int o = rem / (I * K), r2 = rem % (I * K);
    int i = r2 / K, k = r2 % K;
    dst[(size_t)n * OIK + (i * K + k) * O + o] = src[id];
}

// ---------------- conv weight transform: [layer][oc=64][ic=64][3][3] fp32 ->
// f16 fragment layout: idx = (((tap*2+icc)*4+nt)*64 + lane)*8 + j
//   k_local = (lane>>4)*8+j (ic within 32-chunk), oc = nt*16 + (lane&15)
// hi plane at [layer*73728], lo plane (scaled 2048) at +36864.
__global__ void wxform_k(const float* __restrict__ src, _Float16* __restrict__ dst,
                         int nlayers) {
    int id = blockIdx.x * 256 + threadIdx.x;
    if (id >= nlayers * 36864) return;
    int layer = id / 36864, idx = id % 36864;
    int j = idx & 7, l = (idx >> 3) & 63, nt = (idx >> 9) & 3;
    int icc = (idx >> 11) & 1, tap = idx >> 12;
    int kl = (l >> 4) * 8 + j, ic = icc * 32 + kl, oc = nt * 16 + (l & 15);
    float v = src[(size_t)layer * 36864 + (oc * 64 + ic) * 9 + tap];
    _Float16 hi = (_Float16)v;
    _Float16 lo = (_Float16)((v - (float)hi) * LO_SCALE);
    dst[(size_t)layer * 73728 + idx] = hi;
    dst[(size_t)layer * 73728 + 36864 + idx] = lo;
}

// ---------------- conv1: 3->64, 64x64, pad1, +bias, relu, 2x2 maxpool.
// Output NHWC fp32 (B,32,32,64).
__global__ __launch_bounds__(256)
void conv1_k(const float* __restrict__ img, const float* __restrict__ w0t,
             const float* __restrict__ b0, float* __restrict__ out) {
    int b = blockIdx.x, tile = blockIdx.y;
    int typ = (tile >> 1) * 16, txp = (tile & 1) * 16;
    int cy0 = typ * 2, cx0 = txp * 2;
    __shared__ float lds[3][34][34];
    const float* imb = img + (size_t)b * 3 * 64 * 64;
    for (int i = threadIdx.x; i < 3 * 34 * 34; i += 256) {
        int c = i / 1156, rem = i % 1156, r = rem / 34, cc = rem % 34;
        int gy = cy0 - 1 + r, gx = cx0 - 1 + cc;
        float v = 0.f;
        if (gy >= 0 && gy < 64 && gx >= 0 && gx < 64) v = imb[(c * 64 + gy) * 64 + gx];
        lds[c][r][cc] = v;
    }
    __syncthreads();
    int pyl = threadIdx.x >> 4, pxl = threadIdx.x & 15;
    float win[3][4][4];
#pragma unroll
    for (int c = 0; c < 3; ++c)
#pragma unroll
        for (int wy = 0; wy < 4; ++wy)
#pragma unroll
            for (int wx = 0; wx < 4; ++wx)
                win[c][wy][wx] = lds[c][2 * pyl + wy][2 * pxl + wx];
    int py = typ + pyl, px = txp + pxl;
    for (int oc = 0; oc < 64; ++oc) {
        float a00 = 0, a01 = 0, a10 = 0, a11 = 0;
#pragma unroll
        for (int c = 0; c < 3; ++c)
#pragma unroll
            for (int ky = 0; ky < 3; ++ky)
#pragma unroll
                for (int kx = 0; kx < 3; ++kx) {
                    float w = w0t[(c * 9 + ky * 3 + kx) * 64 + oc];
                    a00 = fmaf(win[c][0 + ky][0 + kx], w, a00);
                    a01 = fmaf(win[c][0 + ky][1 + kx], w, a01);
                    a10 = fmaf(win[c][1 + ky][0 + kx], w, a10);
                    a11 = fmaf(win[c][1 + ky][1 + kx], w, a11);
                }
        float bv = b0[oc];
        float v = fmaxf(fmaxf(a00 + bv, 0.f), fmaxf(a01 + bv, 0.f));
        v = fmaxf(v, fmaxf(fmaxf(a10 + bv, 0.f), fmaxf(a11 + bv, 0.f)));
        out[(((size_t)b * 32 + py) * 32 + px) * 64 + oc] = v;  // NHWC
    }
}

// ---------------- MFMA conv 64->64 3x3 pad1, NHWC fp32 in/out.
// Block 256 thr (4 waves), tile 8x16 px. Wave: 2 Mtiles(16px) x 4 Ntiles(16oc).
// Quad-major pixel order: p = Q*4+s, Q=(qy*8+qx), py=qy*2+(s>>1), px=qx*2+(s&1)
//   -> D-frag's 4 regs (row=(lane>>4)*4+reg) form one 2x2 quad -> in-lane pool.
// LDS: halo 10x18 px, 40 f16/pixel (80 B = odd*16B -> uniform bank groups),
// hi plane [0..7200), lo plane (scaled 2048) at +7200. Two ic-chunks of 32.
template <int S, bool POOL, bool RES>
__global__ __launch_bounds__(256, 2)
void convm_k(const float* __restrict__ in, float* __restrict__ out,
             const _Float16* __restrict__ wf, const float* __restrict__ bias,
             const float* __restrict__ res, const int* __restrict__ question,
             int qcol) {
    int b = blockIdx.x, t = blockIdx.y;
    constexpr int NTX = S / 16;  // tiles along x
    int ty0 = (t / NTX) * 8, tx0 = (t % NTX) * 16;

    __shared__ __align__(16) _Float16 lds[2 * 7200];

    int tid = threadIdx.x, lane = tid & 63, wv = tid >> 6;
    const _Float16* wb = wf;
    const float* bb = bias;
    if (question) {
        int idx = question[b * 8 + qcol];
        wb += (size_t)idx * 73728;
        bb += idx * 64;
    }
    float bv[4];
#pragma unroll
    for (int nt = 0; nt < 4; ++nt) bv[nt] = bb[nt * 16 + (lane & 15)];

    f32x4 acc1[2][4] = {};
    f32x4 acc2[2][4] = {};

    int am = lane & 15;          // A-frag row within Mtile
    int k0 = (lane >> 4) * 8;    // A/B-frag k start within 32-chunk

    for (int icc = 0; icc < 2; ++icc) {
        __syncthreads();
        // stage halo 10x18 x 32ic: fp32 -> hi/lo f16 (lo scaled)
        for (int i = tid; i < 1440; i += 256) {
            int pix = i >> 3, j4 = i & 7;
            int hy = pix / 18, hx = pix % 18;
            int gy = ty0 + hy - 1, gx = tx0 + hx - 1;
            float4 v = {0.f, 0.f, 0.f, 0.f};
            if (gy >= 0 && gy < S && gx >= 0 && gx < S)
                v = *(const float4*)&in[(((size_t)b * S + gy) * S + gx) * 64 + icc * 32 + j4 * 4];
            _Float16 h0 = (_Float16)v.x, h1 = (_Float16)v.y;
            _Float16 h2 = (_Float16)v.z, h3 = (_Float16)v.w;
            half4_t hh = {h0, h1, h2, h3};
            half4_t ll = {(_Float16)((v.x - (float)h0) * LO_SCALE),
                          (_Float16)((v.y - (float)h1) * LO_SCALE),
                          (_Float16)((v.z - (float)h2) * LO_SCALE),
                          (_Float16)((v.w - (float)h3) * LO_SCALE)};
            *(half4_t*)&lds[pix * 40 + j4 * 4] = hh;
            *(half4_t*)&lds[7200 + pix * 40 + j4 * 4] = ll;
        }
        __syncthreads();

#pragma unroll
        for (int ky = 0; ky < 3; ++ky)
#pragma unroll
            for (int kx = 0; kx < 3; ++kx) {
                int tap = ky * 3 + kx;
                // B fragments (shared by the wave's 2 Mtiles): 16B/lane coalesced
                const _Float16* wp = wb + (tap * 2 + icc) * 2048 + lane * 8;
                half8 bhi[4], blo[4];
#pragma unroll
                for (int nt = 0; nt < 4; ++nt) {
                    bhi[nt] = *(const half8*)(wp + nt * 512);
                    blo[nt] = *(const half8*)(wp + nt * 512 + 36864);
                }
#pragma unroll
                for (int mt = 0; mt < 2; ++mt) {
                    int MT = wv * 2 + mt;
                    int Q = MT * 4 + (am >> 2), s = am & 3;
                    int py = (Q >> 3) * 2 + (s >> 1), px = (Q & 7) * 2 + (s & 1);
                    const _Float16* ap = &lds[((py + ky) * 18 + (px + kx)) * 40 + k0];
                    half8 ahi = *(const half8*)ap;
                    half8 alo = *(const half8*)(ap + 7200);
#pragma unroll
                    for (int nt = 0; nt < 4; ++nt) {
                        acc1[mt][nt] = __builtin_amdgcn_mfma_f32_16x16x32_f16(
                            ahi, bhi[nt], acc1[mt][nt], 0, 0, 0);
                        acc2[mt][nt] = __builtin_amdgcn_mfma_f32_16x16x32_f16(
                            ahi, blo[nt], acc2[mt][nt], 0, 0, 0);
                        acc2[mt][nt] = __builtin_amdgcn_mfma_f32_16x16x32_f16(
                            alo, bhi[nt], acc2[mt][nt], 0, 0, 0);
                    }
                }
            }
    }

    // epilogue: lane holds oc = nt*16+(lane&15), quad Q = MT*4+(lane>>4), s=reg
    int cn = lane & 15, rq = lane >> 4;
#pragma unroll
    for (int mt = 0; mt < 2; ++mt) {
        int MT = wv * 2 + mt;
        int Q = MT * 4 + rq;
        int qy = Q >> 3, qx = Q & 7;
#pragma unroll
        for (int nt = 0; nt < 4; ++nt) {
            int oc = nt * 16 + cn;
            float vals[4];
#pragma unroll
            for (int r = 0; r < 4; ++r)
                vals[r] = acc1[mt][nt][r] + acc2[mt][nt][r] * LO_INV + bv[nt];
            if (POOL) {
                float m = fmaxf(fmaxf(vals[0], vals[1]), fmaxf(vals[2], vals[3]));
                m = fmaxf(m, 0.f);
                int opy = (ty0 >> 1) + qy, opx = (tx0 >> 1) + qx;
                out[(((size_t)b * (S / 2) + opy) * (S / 2) + opx) * 64 + oc] = m;
            } else {
#pragma unroll
                for (int r = 0; r < 4; ++r) {
                    int py = qy * 2 + (r >> 1), px = qx * 2 + (r & 1);
                    size_t o = (((size_t)b * S + (ty0 + py)) * S + (tx0 + px)) * 64 + oc;
                    float v = vals[r];
                    if (RES) v += res[o];
                    out[o] = fmaxf(v, 0.f);
                }
            }
        }
    }
}

// ---------------- proj: 1x1 conv 64->512 + bias + relu + 2x2 pool.
// Input NHWC (B,16,16,64); output flat k = oc*64 + py*8 + px (matches reshape).
// lane = oc-within-group; LDS reads are wave-broadcast (same pixel all lanes).
__global__ __launch_bounds__(256)
void proj_k(const float* __restrict__ in, const float* __restrict__ wt /*[64][512]*/,
            const float* __restrict__ bias, float* __restrict__ out) {
    int b = blockIdx.x;
    __shared__ float lds[16384];  // [pix][ic]
    const float* inb = in + (size_t)b * 16384;
    for (int i = threadIdx.x; i < 16384; i += 256) lds[i] = inb[i];
    __syncthreads();
    int lane = threadIdx.x & 63, wv = threadIdx.x >> 6;
    int oc = (blockIdx.y * 4 + wv) * 64 + lane;
    float w[64];
#pragma unroll
    for (int ic = 0; ic < 64; ++ic) w[ic] = wt[ic * 512 + oc];
    float bvv = bias[oc];
    for (int pp = 0; pp < 64; ++pp) {
        int ppy = pp >> 3, ppx = pp & 7;
        float m = 0.f;  // relu folded into pool (all candidates >= 0)
#pragma unroll
        for (int d = 0; d < 4; ++d) {
            int py = ppy * 2 + (d >> 1), px = ppx * 2 + (d & 1);
            const float* ap = &lds[(py * 16 + px) * 64];
            float acc = bvv;
#pragma unroll
            for (int ic = 0; ic < 64; ++ic) acc = fmaf(ap[ic], w[ic], acc);
            m = fmaxf(m, acc);
        }
        out[(size_t)b * 32768 + (size_t)oc * 64 + pp] = m;
    }
}

// ---------------- fc1 GEMM: C[256][1024] = A[256][32768] @ W[1024][32768]^T
__global__ __launch_bounds__(256, 4)
void fc1gemm_k(const float* __restrict__ A, const float* __restrict__ W,
               float* __restrict__ partial /* [64][256][1024] */) {
    int bid = blockIdx.x;
    int mt = bid & 1;
    int nt = (bid >> 1) & 7;
    int ks = bid >> 4;
    int m0 = mt * 128, n0 = nt * 128, k0 = ks * 512;
    __shared__ float sa[32][128];
    __shared__ float sb[32][128];
    int tx = threadIdx.x & 15, ty = threadIdx.x >> 4;
    float acc[8][8] = {};
    for (int kt = 0; kt < 16; ++kt) {
        int kk0 = k0 + kt * 32;
        __syncthreads();
#pragma unroll
        for (int pass = 0; pass < 4; ++pass) {
            int idx = pass * 256 + threadIdx.x;
            int row = idx >> 3, c4 = (idx & 7) << 2;
            float4 av = *(const float4*)&A[(size_t)(m0 + row) * 32768 + kk0 + c4];
            sa[c4 + 0][row] = av.x; sa[c4 + 1][row] = av.y;
            sa[c4 + 2][row] = av.z; sa[c4 + 3][row] = av.w;
            float4 wv = *(const float4*)&W[(size_t)(n0 + row) * 32768 + kk0 + c4];
            sb[c4 + 0][row] = wv.x; sb[c4 + 1][row] = wv.y;
            sb[c4 + 2][row] = wv.z; sb[c4 + 3][row] = wv.w;
        }
        __syncthreads();
#pragma unroll 8
        for (int kk = 0; kk < 32; ++kk) {
            float a[8], bvv[8];
            *(float4*)&a[0] = *(const float4*)&sa[kk][ty * 4];
            *(float4*)&a[4] = *(const float4*)&sa[kk][64 + ty * 4];
            *(float4*)&bvv[0] = *(const float4*)&sb[kk][tx * 4];
            *(float4*)&bvv[4] = *(const float4*)&sb[kk][64 + tx * 4];
#pragma unroll
            for (int i = 0; i < 8; ++i)
#pragma unroll
                for (int j = 0; j < 8; ++j)
                    acc[i][j] = fmaf(a[i], bvv[j], acc[i][j]);
        }
    }
#pragma unroll
    for (int i = 0; i < 8; ++i) {
        int m = m0 + ((i < 4) ? ty * 4 + i : 64 + ty * 4 + (i - 4));
#pragma unroll
        for (int jh = 0; jh < 2; ++jh) {
            int n = n0 + jh * 64 + tx * 4;
            float4 v = {acc[i][jh * 4 + 0], acc[i][jh * 4 + 1],
                        acc[i][jh * 4 + 2], acc[i][jh * 4 + 3]};
            *(float4*)&partial[((size_t)ks * 256 + m) * 1024 + n] = v;
        }
    }
}

__global__ __launch_bounds__(256)
void fc1red_k(const float* __restrict__ partial, const float* __restrict__ b1,
              float* __restrict__ fc1o_t /* [n][m] */) {
    int m = blockIdx.x;
    int n0 = threadIdx.x * 4;
    float4 s = {0.f, 0.f, 0.f, 0.f};
    for (int ks = 0; ks < 64; ++ks) {
        float4 v = *(const float4*)&partial[((size_t)ks * 256 + m) * 1024 + n0];
        s.x += v.x; s.y += v.y; s.z += v.z; s.w += v.w;
    }
    fc1o_t[(size_t)(n0 + 0) * 256 + m] = fmaxf(s.x + b1[n0 + 0], 0.f);
    fc1o_t[(size_t)(n0 + 1) * 256 + m] = fmaxf(s.y + b1[n0 + 1], 0.f);
    fc1o_t[(size_t)(n0 + 2) * 256 + m] = fmaxf(s.z + b1[n0 + 2], 0.f);
    fc1o_t[(size_t)(n0 + 3) * 256 + m] = fmaxf(s.w + b1[n0 + 3], 0.f);
}

__global__ __launch_bounds__(256)
void fc2a_k(const float* __restrict__ a_t, const float* __restrict__ W2,
            float* __restrict__ p2) {
    int n2 = blockIdx.x, ks = blockIdx.y;
    int m = threadIdx.x;
    float acc = 0.f;
    for (int k = ks * 256; k < ks * 256 + 256; ++k)
        acc = fmaf(a_t[(size_t)k * 256 + m], W2[n2 * 1024 + k], acc);
    p2[((size_t)n2 * 4 + ks) * 256 + m] = acc;
}

__global__ __launch_bounds__(512)
void fc2b_k(const float* __restrict__ p2, const float* __restrict__ b2,
            float* __restrict__ out) {
    int i = threadIdx.x;
    int m = i >> 1, n2 = i & 1;
    float s = b2[n2];
#pragma unroll
    for (int ks = 0; ks < 4; ++ks) s += p2[((size_t)n2 * 4 + ks) * 256 + m];
    out[m * 2 + n2] = s;
}

// ---------------------------------------------------------------------------
extern "C" void kernel_launch(void* const* d_in, const int* in_sizes, int n_in,
                              void* d_out, int out_size, void* d_ws, size_t ws_size,
                              hipStream_t stream) {
    const float* image   = (const float*)d_in[0];
    const int*   question= (const int*)d_in[1];
    const float* stem_w0 = (const float*)d_in[2];
    const float* stem_b0 = (const float*)d_in[3];
    const float* stem_w  = (const float*)d_in[4];
    const float* stem_b  = (const float*)d_in[5];
    const float* exp_w1  = (const float*)d_in[6];
    const float* exp_b1  = (const float*)d_in[7];
    const float* exp_w2  = (const float*)d_in[8];
    const float* exp_b2  = (const float*)d_in[9];
    const float* proj_w  = (const float*)d_in[10];
    const float* proj_b  = (const float*)d_in[11];
    const float* fc1_w   = (const float*)d_in[12];
    const float* fc1_b   = (const float*)d_in[13];
    const float* fc2_w   = (const float*)d_in[14];
    const float* fc2_b   = (const float*)d_in[15];
    (void)in_sizes; (void)n_in; (void)out_size; (void)ws_size;

    float* ws = (float*)d_ws;
    // Workspace (floats), peak ~156 MB:
    //  [0,A)        p1 NHWC (B,32,32,64); later hA/hB/hC (3*P2N); then fc1 partials
    //  [A,2A)       h2 NHWC; later pool3 (8.39M) + fc1o (0.26M)
    //  [2A,2A+P2N)  p2 NHWC (B,16,16,64)
    //  [2A+P2N,..)  w0t | projt | pfc2 | f16 weight planes (stem/e1/e2)
    const size_t A = 16777216, P2N = 4194304;
    float* p1    = ws;
    float* h2    = ws + A;
    float* p2    = ws + 2 * A;
    float* wtr   = ws + 2 * A + P2N;
    float* w0t   = wtr;                      // 1728 fp32
    float* projt = wtr + 1728;               // 32768 fp32
    float* pfc2  = wtr + 1728 + 32768;       // 2048 fp32
    _Float16* f16b = (_Float16*)(wtr + 36544);  // 16B-aligned
    _Float16* stemtF = f16b;                 // 3 layers * 73728 f16
    _Float16* e1tF   = f16b + 3 * 73728;     // 16 layers
    _Float16* e2tF   = e1tF + 16 * 73728;    // 16 layers
    float* hA    = ws;
    float* hB    = ws + P2N;
    float* hC    = ws + 2 * P2N;
    float* pool3 = h2;
    float* fc1o  = h2 + 8388608;
    float* fc1p  = ws;  // fc1 partials [64][256][1024] after h is consumed... (h=hA read by proj first)

    // weight transforms
    transw_k<<<(1728 + 255) / 256, 256, 0, stream>>>(stem_w0, w0t, 64, 3, 9, 1728);
    transw_k<<<(32768 + 255) / 256, 256, 0, stream>>>(proj_w, projt, 512, 64, 1, 32768);
    wxform_k<<<(3 * 36864 + 255) / 256, 256, 0, stream>>>(stem_w, stemtF, 3);
    wxform_k<<<(16 * 36864 + 255) / 256, 256, 0, stream>>>(exp_w1, e1tF, 16);
    wxform_k<<<(16 * 36864 + 255) / 256, 256, 0, stream>>>(exp_w2, e2tF, 16);

    // stem
    conv1_k<<<dim3(256, 4), 256, 0, stream>>>(image, w0t, stem_b0, p1);
    convm_k<32, false, false><<<dim3(256, 8), 256, 0, stream>>>(
        p1, h2, stemtF, stem_b, nullptr, nullptr, 0);
    convm_k<32, true, false><<<dim3(256, 8), 256, 0, stream>>>(
        h2, p2, stemtF + 73728, stem_b + 64, nullptr, nullptr, 0);
    convm_k<16, false, false><<<dim3(256, 2), 256, 0, stream>>>(
        p2, hA, stemtF + 2 * 73728, stem_b + 128, nullptr, nullptr, 0);

    // expert residual rounds (cols 4,5,7)
    const int cols[3] = {4, 5, 7};
    float* hin = hA;
    float* hmid = hB;
    float* hout = hC;
    for (int r = 0; r < 3; ++r) {
        convm_k<16, false, false><<<dim3(256, 2), 256, 0, stream>>>(
            hin, hmid, e1tF, exp_b1, nullptr, question, cols[r]);
        convm_k<16, false, true><<<dim3(256, 2), 256, 0, stream>>>(
            hmid, hout, e2tF, exp_b2, hin, question, cols[r]);
        float* tp = hin; hin = hout; hout = hmid; hmid = tp;
    }
    // hin == final h (ws+0)

    // head
    proj_k<<<dim3(256, 2), 256, 0, stream>>>(hin, projt, proj_b, pool3);
    fc1gemm_k<<<1024, 256, 0, stream>>>(pool3, fc1_w, fc1p);
    fc1red_k<<<256, 256, 0, stream>>>(fc1p, fc1_b, fc1o);
    fc2a_k<<<dim3(2, 4), 256, 0, stream>>>(fc1o, fc2_w, pfc2);
    fc2b_k<<<1, 512, 0, stream>>>(pfc2, fc2_b, (float*)d_out);
}

// Round 4
// 514.385 us; speedup vs baseline: 4.7185x; 1.2990x over previous
//
#include <hip/hip_runtime.h>
#include <cstddef>

// ---------------------------------------------------------------------------
// SimpleModuleNet. B=256, D=64, E=16, H=W=64, PROJ=512, FC=1024, NA=2.
//
// R2: 64->64 convs on matrix pipe (mfma_f32_16x16x32_f16, f16 hi/lo split,
//     lo plane scaled 2048 -> ~2^-22 error). NHWC activations.
// R3: fc1 on matrix pipe too. In-kernel fp32->f16 hi/lo staging (40-f16 LDS
//     row stride -> conflict-free b128 reads), reg-staged prefetch,
//     XCD-bijective block swizzle for W/A panel L2 reuse, split-K 32.
// ---------------------------------------------------------------------------

typedef _Float16 half8 __attribute__((ext_vector_type(8)));
typedef _Float16 half4_t __attribute__((ext_vector_type(4)));
typedef float f32x4 __attribute__((ext_vector_type(4)));

#define LO_SCALE 2048.0f
#define LO_INV (1.0f / 2048.0f)

// ---------------- generic weight transpose  [o][i](KxK) -> [(i*K+k)][o]
__global__ void transw_k(const float* __restrict__ src, float* __restrict__ dst,
                         int O, int I, int K, int total) {
    int id = blockIdx.x * 256 + threadIdx.x;
    if (id >= total) return;
    int OIK = O * I * K;
    int n = id / OIK, rem = id % OIK;
    int o = rem / (I * K), r2 = rem % (I * K);
    int i = r2 / K, k = r2 % K;
    dst[(size_t)n * OIK + (i * K + k) * O + o] = src[id];
}

// ---------------- conv weight transform: [layer][oc=64][ic=64][3][3] fp32 ->
// f16 fragment layout: idx = (((tap*2+icc)*4+nt)*64 + lane)*8 + j
//   k_local = (lane>>4)*8+j (ic within 32-chunk), oc = nt*16 + (lane&15)
// hi plane at [layer*73728], lo plane (scaled 2048) at +36864.
__global__ void wxform_k(const float* __restrict__ src, _Float16* __restrict__ dst,
                         int nlayers) {
    int id = blockIdx.x * 256 + threadIdx.x;
    if (id >= nlayers * 36864) return;
    int layer = id / 36864, idx = id % 36864;
    int j = idx & 7, l = (idx >> 3) & 63, nt = (idx >> 9) & 3;
    int icc = (idx >> 11) & 1, tap = idx >> 12;
    int kl = (l >> 4) * 8 + j, ic = icc * 32 + kl, oc = nt * 16 + (l & 15);
    float v = src[(size_t)layer * 36864 + (oc * 64 + ic) * 9 + tap];
    _Float16 hi = (_Float16)v;
    _Float16 lo = (_Float16)((v - (float)hi) * LO_SCALE);
    dst[(size_t)layer * 73728 + idx] = hi;
    dst[(size_t)layer * 73728 + 36864 + idx] = lo;
}

// ---------------- conv1: 3->64, 64x64, pad1, +bias, relu, 2x2 maxpool.
// Output NHWC fp32 (B,32,32,64).
__global__ __launch_bounds__(256)
void conv1_k(const float* __restrict__ img, const float* __restrict__ w0t,
             const float* __restrict__ b0, float* __restrict__ out) {
    int b = blockIdx.x, tile = blockIdx.y;
    int typ = (tile >> 1) * 16, txp = (tile & 1) * 16;
    int cy0 = typ * 2, cx0 = txp * 2;
    __shared__ float lds[3][34][34];
    const float* imb = img + (size_t)b * 3 * 64 * 64;
    for (int i = threadIdx.x; i < 3 * 34 * 34; i += 256) {
        int c = i / 1156, rem = i % 1156, r = rem / 34, cc = rem % 34;
        int gy = cy0 - 1 + r, gx = cx0 - 1 + cc;
        float v = 0.f;
        if (gy >= 0 && gy < 64 && gx >= 0 && gx < 64) v = imb[(c * 64 + gy) * 64 + gx];
        lds[c][r][cc] = v;
    }
    __syncthreads();
    int pyl = threadIdx.x >> 4, pxl = threadIdx.x & 15;
    float win[3][4][4];
#pragma unroll
    for (int c = 0; c < 3; ++c)
#pragma unroll
        for (int wy = 0; wy < 4; ++wy)
#pragma unroll
            for (int wx = 0; wx < 4; ++wx)
                win[c][wy][wx] = lds[c][2 * pyl + wy][2 * pxl + wx];
    int py = typ + pyl, px = txp + pxl;
    for (int oc = 0; oc < 64; ++oc) {
        float a00 = 0, a01 = 0, a10 = 0, a11 = 0;
#pragma unroll
        for (int c = 0; c < 3; ++c)
#pragma unroll
            for (int ky = 0; ky < 3; ++ky)
#pragma unroll
                for (int kx = 0; kx < 3; ++kx) {
                    float w = w0t[(c * 9 + ky * 3 + kx) * 64 + oc];
                    a00 = fmaf(win[c][0 + ky][0 + kx], w, a00);
                    a01 = fmaf(win[c][0 + ky][1 + kx], w, a01);
                    a10 = fmaf(win[c][1 + ky][0 + kx], w, a10);
                    a11 = fmaf(win[c][1 + ky][1 + kx], w, a11);
                }
        float bv = b0[oc];
        float v = fmaxf(fmaxf(a00 + bv, 0.f), fmaxf(a01 + bv, 0.f));
        v = fmaxf(v, fmaxf(fmaxf(a10 + bv, 0.f), fmaxf(a11 + bv, 0.f)));
        out[(((size_t)b * 32 + py) * 32 + px) * 64 + oc] = v;  // NHWC
    }
}

// ---------------- MFMA conv 64->64 3x3 pad1, NHWC fp32 in/out.
// Block 256 thr (4 waves), tile 8x16 px. Wave: 2 Mtiles(16px) x 4 Ntiles(16oc).
// Quad-major pixel order -> D-frag's 4 regs form one 2x2 quad -> in-lane pool.
// LDS: halo 10x18 px, 40 f16/pixel (80 B stride), hi plane + lo plane (+7200).
template <int S, bool POOL, bool RES>
__global__ __launch_bounds__(256, 2)
void convm_k(const float* __restrict__ in, float* __restrict__ out,
             const _Float16* __restrict__ wf, const float* __restrict__ bias,
             const float* __restrict__ res, const int* __restrict__ question,
             int qcol) {
    int b = blockIdx.x, t = blockIdx.y;
    constexpr int NTX = S / 16;  // tiles along x
    int ty0 = (t / NTX) * 8, tx0 = (t % NTX) * 16;

    __shared__ __align__(16) _Float16 lds[2 * 7200];

    int tid = threadIdx.x, lane = tid & 63, wv = tid >> 6;
    const _Float16* wb = wf;
    const float* bb = bias;
    if (question) {
        int idx = question[b * 8 + qcol];
        wb += (size_t)idx * 73728;
        bb += idx * 64;
    }
    float bv[4];
#pragma unroll
    for (int nt = 0; nt < 4; ++nt) bv[nt] = bb[nt * 16 + (lane & 15)];

    f32x4 acc1[2][4] = {};
    f32x4 acc2[2][4] = {};

    int am = lane & 15;          // A-frag row within Mtile
    int k0 = (lane >> 4) * 8;    // A/B-frag k start within 32-chunk

    for (int icc = 0; icc < 2; ++icc) {
        __syncthreads();
        for (int i = tid; i < 1440; i += 256) {
            int pix = i >> 3, j4 = i & 7;
            int hy = pix / 18, hx = pix % 18;
            int gy = ty0 + hy - 1, gx = tx0 + hx - 1;
            float4 v = {0.f, 0.f, 0.f, 0.f};
            if (gy >= 0 && gy < S && gx >= 0 && gx < S)
                v = *(const float4*)&in[(((size_t)b * S + gy) * S + gx) * 64 + icc * 32 + j4 * 4];
            _Float16 h0 = (_Float16)v.x, h1 = (_Float16)v.y;
            _Float16 h2 = (_Float16)v.z, h3 = (_Float16)v.w;
            half4_t hh = {h0, h1, h2, h3};
            half4_t ll = {(_Float16)((v.x - (float)h0) * LO_SCALE),
                          (_Float16)((v.y - (float)h1) * LO_SCALE),
                          (_Float16)((v.z - (float)h2) * LO_SCALE),
                          (_Float16)((v.w - (float)h3) * LO_SCALE)};
            *(half4_t*)&lds[pix * 40 + j4 * 4] = hh;
            *(half4_t*)&lds[7200 + pix * 40 + j4 * 4] = ll;
        }
        __syncthreads();

#pragma unroll
        for (int ky = 0; ky < 3; ++ky)
#pragma unroll
            for (int kx = 0; kx < 3; ++kx) {
                int tap = ky * 3 + kx;
                const _Float16* wp = wb + (tap * 2 + icc) * 2048 + lane * 8;
                half8 bhi[4], blo[4];
#pragma unroll
                for (int nt = 0; nt < 4; ++nt) {
                    bhi[nt] = *(const half8*)(wp + nt * 512);
                    blo[nt] = *(const half8*)(wp + nt * 512 + 36864);
                }
#pragma unroll
                for (int mt = 0; mt < 2; ++mt) {
                    int MT = wv * 2 + mt;
                    int Q = MT * 4 + (am >> 2), s = am & 3;
                    int py = (Q >> 3) * 2 + (s >> 1), px = (Q & 7) * 2 + (s & 1);
                    const _Float16* ap = &lds[((py + ky) * 18 + (px + kx)) * 40 + k0];
                    half8 ahi = *(const half8*)ap;
                    half8 alo = *(const half8*)(ap + 7200);
#pragma unroll
                    for (int nt = 0; nt < 4; ++nt) {
                        acc1[mt][nt] = __builtin_amdgcn_mfma_f32_16x16x32_f16(
                            ahi, bhi[nt], acc1[mt][nt], 0, 0, 0);
                        acc2[mt][nt] = __builtin_amdgcn_mfma_f32_16x16x32_f16(
                            ahi, blo[nt], acc2[mt][nt], 0, 0, 0);
                        acc2[mt][nt] = __builtin_amdgcn_mfma_f32_16x16x32_f16(
                            alo, bhi[nt], acc2[mt][nt], 0, 0, 0);
                    }
                }
            }
    }

    int cn = lane & 15, rq = lane >> 4;
#pragma unroll
    for (int mt = 0; mt < 2; ++mt) {
        int MT = wv * 2 + mt;
        int Q = MT * 4 + rq;
        int qy = Q >> 3, qx = Q & 7;
#pragma unroll
        for (int nt = 0; nt < 4; ++nt) {
            int oc = nt * 16 + cn;
            float vals[4];
#pragma unroll
            for (int r = 0; r < 4; ++r)
                vals[r] = acc1[mt][nt][r] + acc2[mt][nt][r] * LO_INV + bv[nt];
            if (POOL) {
                float m = fmaxf(fmaxf(vals[0], vals[1]), fmaxf(vals[2], vals[3]));
                m = fmaxf(m, 0.f);
                int opy = (ty0 >> 1) + qy, opx = (tx0 >> 1) + qx;
                out[(((size_t)b * (S / 2) + opy) * (S / 2) + opx) * 64 + oc] = m;
            } else {
#pragma unroll
                for (int r = 0; r < 4; ++r) {
                    int py = qy * 2 + (r >> 1), px = qx * 2 + (r & 1);
                    size_t o = (((size_t)b * S + (ty0 + py)) * S + (tx0 + px)) * 64 + oc;
                    float v = vals[r];
                    if (RES) v += res[o];
                    out[o] = fmaxf(v, 0.f);
                }
            }
        }
    }
}

// ---------------- proj: 1x1 conv 64->512 + bias + relu + 2x2 pool.
__global__ __launch_bounds__(256)
void proj_k(const float* __restrict__ in, const float* __restrict__ wt /*[64][512]*/,
            const float* __restrict__ bias, float* __restrict__ out) {
    int b = blockIdx.x;
    __shared__ float lds[16384];  // [pix][ic]
    const float* inb = in + (size_t)b * 16384;
    for (int i = threadIdx.x; i < 16384; i += 256) lds[i] = inb[i];
    __syncthreads();
    int lane = threadIdx.x & 63, wv = threadIdx.x >> 6;
    int oc = (blockIdx.y * 4 + wv) * 64 + lane;
    float w[64];
#pragma unroll
    for (int ic = 0; ic < 64; ++ic) w[ic] = wt[ic * 512 + oc];
    float bvv = bias[oc];
    for (int pp = 0; pp < 64; ++pp) {
        int ppy = pp >> 3, ppx = pp & 7;
        float m = 0.f;
#pragma unroll
        for (int d = 0; d < 4; ++d) {
            int py = ppy * 2 + (d >> 1), px = ppx * 2 + (d & 1);
            const float* ap = &lds[(py * 16 + px) * 64];
            float acc = bvv;
#pragma unroll
            for (int ic = 0; ic < 64; ++ic) acc = fmaf(ap[ic], w[ic], acc);
            m = fmaxf(m, acc);
        }
        out[(size_t)b * 32768 + (size_t)oc * 64 + pp] = m;
    }
}

// ---------------- fc1 MFMA GEMM: C[256][1024] = A[256][32768] @ W[1024][32768]^T
// f16 hi/lo split (3 MFMAs), in-kernel conversion. 512 blocks =
// mt(2) x nt(8) x ks(32), XCD-bijective swizzle so logical-consecutive blocks
// (sharing A/W panels) run on one XCD's L2. Block tile 128x128, K-step 32.
// LDS rows stride 40 f16 (80 B) -> <=2-way (free) bank aliasing on b128 reads.
__global__ __launch_bounds__(256)
void fc1m_k(const float* __restrict__ A, const float* __restrict__ W,
            float* __restrict__ partial /* [32][256][1024] */) {
    int bid = blockIdx.x;
    int lid = (bid & 7) * 64 + (bid >> 3);   // bijective, 512 % 8 == 0
    int mt = lid & 1, nt = (lid >> 1) & 7, ks = lid >> 4;
    int m0 = mt * 128, n0 = nt * 128;
    const float* Ab = A + (size_t)m0 * 32768 + ks * 1024;
    const float* Wb = W + (size_t)n0 * 32768 + ks * 1024;

    __shared__ __align__(16) _Float16 lds[20480];  // A hi|lo, B hi|lo: 4x5120
    _Float16* sa = lds;
    _Float16* sb = lds + 10240;

    int tid = threadIdx.x, lane = tid & 63, wv = tid >> 6;
    int wm = (wv & 1) * 64, wn = (wv >> 1) * 64;

    f32x4 acc1[4][4] = {};
    f32x4 acc2[4][4] = {};

    int row[4], c4[4];
#pragma unroll
    for (int p = 0; p < 4; ++p) {
        int idx = p * 256 + tid;
        row[p] = idx >> 3;
        c4[p] = (idx & 7) << 2;
    }

    float4 ra[4], rw[4];
#pragma unroll
    for (int p = 0; p < 4; ++p) {
        ra[p] = *(const float4*)&Ab[(size_t)row[p] * 32768 + c4[p]];
        rw[p] = *(const float4*)&Wb[(size_t)row[p] * 32768 + c4[p]];
    }

    for (int kt = 0; kt < 32; ++kt) {
#pragma unroll
        for (int p = 0; p < 4; ++p) {
            float4 v = ra[p];
            _Float16 h0 = (_Float16)v.x, h1 = (_Float16)v.y;
            _Float16 h2 = (_Float16)v.z, h3 = (_Float16)v.w;
            half4_t hh = {h0, h1, h2, h3};
            half4_t ll = {(_Float16)((v.x - (float)h0) * LO_SCALE),
                          (_Float16)((v.y - (float)h1) * LO_SCALE),
                          (_Float16)((v.z - (float)h2) * LO_SCALE),
                          (_Float16)((v.w - (float)h3) * LO_SCALE)};
            *(half4_t*)&sa[row[p] * 40 + c4[p]] = hh;
            *(half4_t*)&sa[5120 + row[p] * 40 + c4[p]] = ll;
            float4 u = rw[p];
            _Float16 g0 = (_Float16)u.x, g1 = (_Float16)u.y;
            _Float16 g2 = (_Float16)u.z, g3 = (_Float16)u.w;
            half4_t gh = {g0, g1, g2, g3};
            half4_t gl = {(_Float16)((u.x - (float)g0) * LO_SCALE),
                          (_Float16)((u.y - (float)g1) * LO_SCALE),
                          (_Float16)((u.z - (float)g2) * LO_SCALE),
                          (_Float16)((u.w - (float)g3) * LO_SCALE)};
            *(half4_t*)&sb[row[p] * 40 + c4[p]] = gh;
            *(half4_t*)&sb[5120 + row[p] * 40 + c4[p]] = gl;
        }
        __syncthreads();
        if (kt < 31) {  // issue next k-step loads; latency hides under MFMAs
            int kb = (kt + 1) * 32;
#pragma unroll
            for (int p = 0; p < 4; ++p) {
                ra[p] = *(const float4*)&Ab[(size_t)row[p] * 32768 + kb + c4[p]];
                rw[p] = *(const float4*)&Wb[(size_t)row[p] * 32768 + kb + c4[p]];
            }
        }
        int koff = (lane >> 4) * 8;
        int fr = lane & 15;
        half8 bh[4], bl[4];
#pragma unroll
        for (int nf = 0; nf < 4; ++nf) {
            int r = wn + nf * 16 + fr;
            bh[nf] = *(const half8*)&sb[r * 40 + koff];
            bl[nf] = *(const half8*)&sb[5120 + r * 40 + koff];
        }
#pragma unroll
        for (int mf = 0; mf < 4; ++mf) {
            int r = wm + mf * 16 + fr;
            half8 ah = *(const half8*)&sa[r * 40 + koff];
            half8 al = *(const half8*)&sa[5120 + r * 40 + koff];
#pragma unroll
            for (int nf = 0; nf < 4; ++nf) {
                acc1[mf][nf] = __builtin_amdgcn_mfma_f32_16x16x32_f16(
                    ah, bh[nf], acc1[mf][nf], 0, 0, 0);
                acc2[mf][nf] = __builtin_amdgcn_mfma_f32_16x16x32_f16(
                    ah, bl[nf], acc2[mf][nf], 0, 0, 0);
                acc2[mf][nf] = __builtin_amdgcn_mfma_f32_16x16x32_f16(
                    al, bh[nf], acc2[mf][nf], 0, 0, 0);
            }
        }
        __syncthreads();
    }

    int rq = lane >> 4, cn = lane & 15;
    float* pb = partial + (size_t)ks * 262144;
#pragma unroll
    for (int mf = 0; mf < 4; ++mf)
#pragma unroll
        for (int nf = 0; nf < 4; ++nf) {
            int n = n0 + wn + nf * 16 + cn;
#pragma unroll
            for (int r = 0; r < 4; ++r) {
                int m = m0 + wm + mf * 16 + rq * 4 + r;
                pb[(size_t)m * 1024 + n] = acc1[mf][nf][r] + acc2[mf][nf][r] * LO_INV;
            }
        }
}

__global__ __launch_bounds__(256)
void fc1red_k(const float* __restrict__ partial, const float* __restrict__ b1,
              float* __restrict__ fc1o_t /* [n][m] */) {
    int m = blockIdx.x;
    int n0 = threadIdx.x * 4;
    float4 s = {0.f, 0.f, 0.f, 0.f};
    for (int ks = 0; ks < 32; ++ks) {
        float4 v = *(const float4*)&partial[((size_t)ks * 256 + m) * 1024 + n0];
        s.x += v.x; s.y += v.y; s.z += v.z; s.w += v.w;
    }
    fc1o_t[(size_t)(n0 + 0) * 256 + m] = fmaxf(s.x + b1[n0 + 0], 0.f);
    fc1o_t[(size_t)(n0 + 1) * 256 + m] = fmaxf(s.y + b1[n0 + 1], 0.f);
    fc1o_t[(size_t)(n0 + 2) * 256 + m] = fmaxf(s.z + b1[n0 + 2], 0.f);
    fc1o_t[(size_t)(n0 + 3) * 256 + m] = fmaxf(s.w + b1[n0 + 3], 0.f);
}

__global__ __launch_bounds__(256)
void fc2a_k(const float* __restrict__ a_t, const float* __restrict__ W2,
            float* __restrict__ p2) {
    int n2 = blockIdx.x, ks = blockIdx.y;
    int m = threadIdx.x;
    float acc = 0.f;
    for (int k = ks * 256; k < ks * 256 + 256; ++k)
        acc = fmaf(a_t[(size_t)k * 256 + m], W2[n2 * 1024 + k], acc);
    p2[((size_t)n2 * 4 + ks) * 256 + m] = acc;
}

__global__ __launch_bounds__(512)
void fc2b_k(const float* __restrict__ p2, const float* __restrict__ b2,
            float* __restrict__ out) {
    int i = threadIdx.x;
    int m = i >> 1, n2 = i & 1;
    float s = b2[n2];
#pragma unroll
    for (int ks = 0; ks < 4; ++ks) s += p2[((size_t)n2 * 4 + ks) * 256 + m];
    out[m * 2 + n2] = s;
}

// ---------------------------------------------------------------------------
extern "C" void kernel_launch(void* const* d_in, const int* in_sizes, int n_in,
                              void* d_out, int out_size, void* d_ws, size_t ws_size,
                              hipStream_t stream) {
    const float* image   = (const float*)d_in[0];
    const int*   question= (const int*)d_in[1];
    const float* stem_w0 = (const float*)d_in[2];
    const float* stem_b0 = (const float*)d_in[3];
    const float* stem_w  = (const float*)d_in[4];
    const float* stem_b  = (const float*)d_in[5];
    const float* exp_w1  = (const float*)d_in[6];
    const float* exp_b1  = (const float*)d_in[7];
    const float* exp_w2  = (const float*)d_in[8];
    const float* exp_b2  = (const float*)d_in[9];
    const float* proj_w  = (const float*)d_in[10];
    const float* proj_b  = (const float*)d_in[11];
    const float* fc1_w   = (const float*)d_in[12];
    const float* fc1_b   = (const float*)d_in[13];
    const float* fc2_w   = (const float*)d_in[14];
    const float* fc2_b   = (const float*)d_in[15];
    (void)in_sizes; (void)n_in; (void)out_size; (void)ws_size;

    float* ws = (float*)d_ws;
    // Workspace (floats), peak ~156 MB:
    //  [0,A)        p1 NHWC (B,32,32,64); later hA/hB/hC (3*P2N); then fc1
    //               partials [32][256][1024] (8.4M floats)
    //  [A,2A)       h2 NHWC; later pool3 (8.39M) + fc1o (0.26M)
    //  [2A,2A+P2N)  p2 NHWC (B,16,16,64)
    //  [2A+P2N,..)  w0t | projt | pfc2 | f16 weight planes (stem/e1/e2)
    const size_t A = 16777216, P2N = 4194304;
    float* p1    = ws;
    float* h2    = ws + A;
    float* p2    = ws + 2 * A;
    float* wtr   = ws + 2 * A + P2N;
    float* w0t   = wtr;                      // 1728 fp32
    float* projt = wtr + 1728;               // 32768 fp32
    float* pfc2  = wtr + 1728 + 32768;       // 2048 fp32
    _Float16* f16b = (_Float16*)(wtr + 36544);  // 16B-aligned
    _Float16* stemtF = f16b;                 // 3 layers * 73728 f16
    _Float16* e1tF   = f16b + 3 * 73728;     // 16 layers
    _Float16* e2tF   = e1tF + 16 * 73728;    // 16 layers
    float* hA    = ws;
    float* hB    = ws + P2N;
    float* hC    = ws + 2 * P2N;
    float* pool3 = h2;
    float* fc1o  = h2 + 8388608;
    float* fc1p  = ws;  // fc1 partials [32][256][1024] (hA dead after proj)

    // weight transforms
    transw_k<<<(1728 + 255) / 256, 256, 0, stream>>>(stem_w0, w0t, 64, 3, 9, 1728);
    transw_k<<<(32768 + 255) / 256, 256, 0, stream>>>(proj_w, projt, 512, 64, 1, 32768);
    wxform_k<<<(3 * 36864 + 255) / 256, 256, 0, stream>>>(stem_w, stemtF, 3);
    wxform_k<<<(16 * 36864 + 255) / 256, 256, 0, stream>>>(exp_w1, e1tF, 16);
    wxform_k<<<(16 * 36864 + 255) / 256, 256, 0, stream>>>(exp_w2, e2tF, 16);

    // stem
    conv1_k<<<dim3(256, 4), 256, 0, stream>>>(image, w0t, stem_b0, p1);
    convm_k<32, false, false><<<dim3(256, 8), 256, 0, stream>>>(
        p1, h2, stemtF, stem_b, nullptr, nullptr, 0);
    convm_k<32, true, false><<<dim3(256, 8), 256, 0, stream>>>(
        h2, p2, stemtF + 73728, stem_b + 64, nullptr, nullptr, 0);
    convm_k<16, false, false><<<dim3(256, 2), 256, 0, stream>>>(
        p2, hA, stemtF + 2 * 73728, stem_b + 128, nullptr, nullptr, 0);

    // expert residual rounds (cols 4,5,7)
    const int cols[3] = {4, 5, 7};
    float* hin = hA;
    float* hmid = hB;
    float* hout = hC;
    for (int r = 0; r < 3; ++r) {
        convm_k<16, false, false><<<dim3(256, 2), 256, 0, stream>>>(
            hin, hmid, e1tF, exp_b1, nullptr, question, cols[r]);
        convm_k<16, false, true><<<dim3(256, 2), 256, 0, stream>>>(
            hmid, hout, e2tF, exp_b2, hin, question, cols[r]);
        float* tp = hin; hin = hout; hout = hmid; hmid = tp;
    }
    // hin == final h (ws+0)

    // head
    proj_k<<<dim3(256, 2), 256, 0, stream>>>(hin, projt, proj_b, pool3);
    fc1m_k<<<512, 256, 0, stream>>>(pool3, fc1_w, fc1p);
    fc1red_k<<<256, 256, 0, stream>>>(fc1p, fc1_b, fc1o);
    fc2a_k<<<dim3(2, 4), 256, 0, stream>>>(fc1o, fc2_w, pfc2);
    fc2b_k<<<1, 512, 0, stream>>>(pfc2, fc2_b, (float*)d_out);
}